// Round 10
// baseline (133.449 us; speedup 1.0000x reference)
//
#include <hip/hip_runtime.h>
#include <math.h>

#define T_SEQ 2048
#define D_MODEL 1024
#define DH 128
#define FRAG_B 262144      // frag-plane elems per batch: 128*4*512 (= 64*8*512)

typedef __bf16 bfx8 __attribute__((ext_vector_type(8)));
typedef float f32x4 __attribute__((ext_vector_type(4)));

union U16x8 { uint4 u4; unsigned int ui[4]; unsigned short us[8]; __bf16 bf[8]; bfx8 v; };

__device__ inline uint4 cvt8u(float4 a, float4 b) {
    U16x8 u;
    u.bf[0] = (__bf16)a.x; u.bf[1] = (__bf16)a.y; u.bf[2] = (__bf16)a.z; u.bf[3] = (__bf16)a.w;
    u.bf[4] = (__bf16)b.x; u.bf[5] = (__bf16)b.y; u.bf[6] = (__bf16)b.z; u.bf[7] = (__bf16)b.w;
    return u.u4;
}

// ---------------- Kernel P: W fp32 -> bf16 (once) ----------------
__global__ __launch_bounds__(256) void wcvt_kernel(
    const float* __restrict__ Wq, const float* __restrict__ Wk,
    const float* __restrict__ Wv, __bf16* __restrict__ Wb)
{
    const int i = blockIdx.x * 256 + threadIdx.x;
    const int plane = i >> 14;
    const int off = (i & 16383) * 8;
    const float* src = (plane == 0) ? Wq : (plane == 1) ? Wk : Wv;
    float4 a = *(const float4*)(src + off);
    float4 b = *(const float4*)(src + off + 4);
    *(uint4*)&Wb[(size_t)plane * (DH * D_MODEL) + off] = cvt8u(a, b);
}

// ---------------- Kernel Z: zero the fp32 accumulators ----------------
// N = B*T*DH + B*T floats = 4,202,496 = 4104 blocks * 256 threads * 4 floats
__global__ __launch_bounds__(256) void zero_kernel(float* __restrict__ p)
{
    const size_t i = ((size_t)blockIdx.x * 256 + threadIdx.x) * 4;
    *(float4*)(p + i) = make_float4(0.f, 0.f, 0.f, 0.f);
}

// ---------------- Kernel A: QKV GEMM -> fragment-order planes ----------------
// grid 3*M/64 blocks of 256 (4 waves, 64m x 128n tile; wave 32m x 64n). BK=64 dbuf,
// one barrier/slab. Epilogue: RoPE (Q,K) then LDS re-tile into MFMA fragment order:
//   QF/KF[b][t16][c4][lane][8] ; VF[b][t32][j][lane][8]  (1 KB contiguous per frag)
__global__ __launch_bounds__(256) void qkv_kernel(
    const float* __restrict__ x, const __bf16* __restrict__ Wb,
    const float* __restrict__ theta,
    __bf16* __restrict__ QF, __bf16* __restrict__ KF, __bf16* __restrict__ VF, int M)
{
    __shared__ __align__(16) unsigned short As[2][64 * 72];    // 18 KB
    __shared__ __align__(16) unsigned short Bs[2][128 * 72];   // 36 KB

    const int ntile = M / 64;
    const int bx = blockIdx.x;
    const int wsel = bx / ntile;
    const int m0 = (bx - wsel * ntile) * 64;

    const int tid = threadIdx.x;
    const int ln = tid & 63, wv = tid >> 6;
    const int lo = ln & 15, quad = ln >> 4;
    const int hi8 = quad * 8;
    const int wm = (wv & 1) * 32;
    const int wn = (wv >> 1) * 64;

    const int arow = tid >> 2, aseg = (tid & 3) * 16;
    const int brow = tid >> 1, bseg = (tid & 1) * 32;
    const float*  axp = x + (size_t)(m0 + arow) * D_MODEL + aseg;
    const __bf16* bwp = Wb + (size_t)wsel * (DH * D_MODEL) + (size_t)brow * D_MODEL + bseg;

    float4 ar[4];
    uint4  br[4];
    #pragma unroll
    for (int q = 0; q < 4; ++q) ar[q] = *(const float4*)(axp + q * 4);
    #pragma unroll
    for (int q = 0; q < 4; ++q) br[q] = *(const uint4*)(bwp + q * 8);

    *(uint4*)&As[0][arow * 72 + aseg]     = cvt8u(ar[0], ar[1]);
    *(uint4*)&As[0][arow * 72 + aseg + 8] = cvt8u(ar[2], ar[3]);
    #pragma unroll
    for (int q = 0; q < 4; ++q) *(uint4*)&Bs[0][brow * 72 + bseg + q * 8] = br[q];
    __syncthreads();

    f32x4 acc[2][4];
    #pragma unroll
    for (int i = 0; i < 2; ++i)
        #pragma unroll
        for (int j = 0; j < 4; ++j) acc[i][j] = (f32x4)(0.f);

    for (int s = 0; s < 16; ++s) {
        const int cur = s & 1;
        if (s < 15) {
            const int kc = (s + 1) * 64;
            #pragma unroll
            for (int q = 0; q < 4; ++q) ar[q] = *(const float4*)(axp + kc + q * 4);
            #pragma unroll
            for (int q = 0; q < 4; ++q) br[q] = *(const uint4*)(bwp + kc + q * 8);
        }

        bfx8 af[2][2], bfr[4][2];
        #pragma unroll
        for (int i = 0; i < 2; ++i)
            #pragma unroll
            for (int s2 = 0; s2 < 2; ++s2)
                af[i][s2] = *(const bfx8*)&As[cur][(wm + i * 16 + lo) * 72 + s2 * 32 + hi8];
        #pragma unroll
        for (int j = 0; j < 4; ++j)
            #pragma unroll
            for (int s2 = 0; s2 < 2; ++s2)
                bfr[j][s2] = *(const bfx8*)&Bs[cur][(wn + j * 16 + lo) * 72 + s2 * 32 + hi8];
        #pragma unroll
        for (int s2 = 0; s2 < 2; ++s2)
            #pragma unroll
            for (int i = 0; i < 2; ++i)
                #pragma unroll
                for (int j = 0; j < 4; ++j)
                    acc[i][j] = __builtin_amdgcn_mfma_f32_16x16x32_bf16(af[i][s2], bfr[j][s2], acc[i][j], 0, 0, 0);

        if (s < 15) {
            const int nxt = cur ^ 1;
            *(uint4*)&As[nxt][arow * 72 + aseg]     = cvt8u(ar[0], ar[1]);
            *(uint4*)&As[nxt][arow * 72 + aseg + 8] = cvt8u(ar[2], ar[3]);
            #pragma unroll
            for (int q = 0; q < 4; ++q) *(uint4*)&Bs[nxt][brow * 72 + bseg + q * 8] = br[q];
            __syncthreads();
        }
    }

    const int b = m0 >> 11;
    const int mloc0 = m0 & (T_SEQ - 1);

    if (wsel < 2) {
        // RoPE in-register, then LDS re-tile [mloc][h] stride 136, then frag write.
        __syncthreads();
        unsigned short* T = &Bs[0][0];   // 64 x 136 = 8704 <= 9216
        #pragma unroll
        for (int j = 0; j < 4; ++j) {
            const int h = wn + j * 16 + lo;
            const float th = theta[h];
            #pragma unroll
            for (int i = 0; i < 2; ++i) {
                #pragma unroll
                for (int r = 0; r < 4; ++r) {
                    const int mloc = wm + i * 16 + quad * 4 + r;
                    float v = acc[i][j][r];
                    float partner = __shfl_xor(v, 1, 64);
                    float ang = (float)(mloc0 + mloc + 1) * th;
                    float rev = ang * 0.15915494309189535f;   // 1/(2*pi)
                    rev -= floorf(rev);
                    float sn = __builtin_amdgcn_sinf(rev);
                    float cs = __builtin_amdgcn_cosf(rev);
                    float res = (h & 1) ? (v * cs - partner * sn)
                                        : (v * cs + partner * sn);
                    U16x8 u; u.bf[0] = (__bf16)res;
                    T[mloc * 136 + h] = u.us[0];
                }
            }
        }
        __syncthreads();
        const int g = tid >> 6, L = tid & 63;
        const int lo2 = L & 15, q2 = L >> 4;
        __bf16* dst = (wsel == 0 ? QF : KF) + (size_t)b * FRAG_B
                    + (size_t)(((mloc0 >> 4) + g) * 4) * 512 + L * 8;
        #pragma unroll
        for (int c4 = 0; c4 < 4; ++c4)
            *(uint4*)(dst + c4 * 512) = *(const uint4*)&T[(g * 16 + lo2) * 136 + c4 * 32 + q2 * 8];
    } else {
        // V: LDS transpose [h][t_loc] stride 72, then frag write (frag rows = h).
        __syncthreads();
        unsigned short* VT = &As[0][0];   // 128 x 72 = 9216
        #pragma unroll
        for (int j = 0; j < 4; ++j) {
            const int h = wn + j * 16 + lo;
            #pragma unroll
            for (int i = 0; i < 2; ++i)
                #pragma unroll
                for (int r = 0; r < 4; ++r) {
                    U16x8 u; u.bf[0] = (__bf16)acc[i][j][r];
                    VT[h * 72 + wm + i * 16 + quad * 4 + r] = u.us[0];
                }
        }
        __syncthreads();
        const int g = tid >> 6, L = tid & 63;
        const int lo2 = L & 15, q2 = L >> 4;
        const int kb = mloc0 >> 5;
        #pragma unroll
        for (int f = 0; f < 4; ++f) {
            const int fid = g * 4 + f;
            const int kt = fid >> 3, j = fid & 7;
            __bf16* dst = VF + (size_t)b * FRAG_B + (size_t)((kb + kt) * 8 + j) * 512 + L * 8;
            *(uint4*)dst = *(const uint4*)&VT[(j * 16 + lo2) * 72 + kt * 32 + q2 * 8];
        }
    }
}

// ---------------- Kernel B: wave-autonomous attention -> fp32 atomic accumulate ----------------
// grid (64 qt, 8 c, B), block 64 = ONE wave: 32 q-rows x 256-k chunk, <=8 tiles of 32.
// All operand loads contiguous 1 KB wave reads; K frags prefetched depth-1. Partial
// O (fp32, unnormalized) and l accumulated straight into Oacc/Lacc via HW fp32 atomics.
__global__ __launch_bounds__(64) void attn_partial_kernel(
    const __bf16* __restrict__ QF, const __bf16* __restrict__ KF,
    const __bf16* __restrict__ VF,
    float* __restrict__ Oacc, float* __restrict__ Lacc)
{
    const int qt = blockIdx.x, c = blockIdx.y, b = blockIdx.z;
    const int qbase = qt * 32;
    const int kstart = c << 8;
    if (kstart > qbase) return;
    const int nt = min(8, (qbase + 32 - kstart) >> 5);

    __shared__ __align__(16) unsigned short Pw[2 * 640];

    const int ln = threadIdx.x;
    const int lo = ln & 15, quad = ln >> 4;
    const int hi8 = quad * 8;

    const __bf16* QFb = QF + (size_t)b * FRAG_B;
    const __bf16* KFb = KF + (size_t)b * FRAG_B;
    const __bf16* VFb = VF + (size_t)b * FRAG_B;

    bfx8 qf[2][4];
    #pragma unroll
    for (int iq = 0; iq < 2; ++iq)
        #pragma unroll
        for (int c4 = 0; c4 < 4; ++c4)
            qf[iq][c4] = *(const bfx8*)&QFb[(size_t)((qt * 2 + iq) * 4 + c4) * 512 + ln * 8];

    f32x4 O[2][8];
    #pragma unroll
    for (int iq = 0; iq < 2; ++iq)
        #pragma unroll
        for (int j = 0; j < 8; ++j) O[iq][j] = (f32x4)(0.f);
    float lsum[2][4];
    #pragma unroll
    for (int iq = 0; iq < 2; ++iq)
        #pragma unroll
        for (int r = 0; r < 4; ++r) lsum[iq][r] = 0.f;

    bfx8 kcur[2][4], knxt[2][4];
    #pragma unroll
    for (int jj = 0; jj < 2; ++jj)
        #pragma unroll
        for (int c4 = 0; c4 < 4; ++c4)
            kcur[jj][c4] = *(const bfx8*)&KFb[(size_t)(((kstart >> 4) + jj) * 4 + c4) * 512 + ln * 8];

    for (int kt = 0; kt < nt; ++kt) {
        const int k0 = kstart + kt * 32;
        bfx8 vf[8];
        #pragma unroll
        for (int j = 0; j < 8; ++j)
            vf[j] = *(const bfx8*)&VFb[(size_t)((k0 >> 5) * 8 + j) * 512 + ln * 8];
        if (kt + 1 < nt) {
            const int kn16 = (k0 + 32) >> 4;
            #pragma unroll
            for (int jj = 0; jj < 2; ++jj)
                #pragma unroll
                for (int c4 = 0; c4 < 4; ++c4)
                    knxt[jj][c4] = *(const bfx8*)&KFb[(size_t)((kn16 + jj) * 4 + c4) * 512 + ln * 8];
        }

        f32x4 s4[2][2];
        #pragma unroll
        for (int iq = 0; iq < 2; ++iq)
            #pragma unroll
            for (int jj = 0; jj < 2; ++jj) s4[iq][jj] = (f32x4)(0.f);
        #pragma unroll
        for (int c4 = 0; c4 < 4; ++c4)
            #pragma unroll
            for (int iq = 0; iq < 2; ++iq)
                #pragma unroll
                for (int jj = 0; jj < 2; ++jj)
                    s4[iq][jj] = __builtin_amdgcn_mfma_f32_16x16x32_bf16(qf[iq][c4], kcur[jj][c4], s4[iq][jj], 0, 0, 0);

        const bool needMask = (k0 + 31 > qbase);
        #pragma unroll
        for (int iq = 0; iq < 2; ++iq)
            #pragma unroll
            for (int jj = 0; jj < 2; ++jj)
                #pragma unroll
                for (int r = 0; r < 4; ++r) {
                    const int col = k0 + jj * 16 + lo;
                    const int row = qbase + iq * 16 + quad * 4 + r;
                    float p = __expf(s4[iq][jj][r] * 0.03125f);   // scale 1024^-0.5
                    if (needMask && col > row) p = 0.f;
                    lsum[iq][r] += p;
                    U16x8 u; u.bf[0] = (__bf16)p;
                    Pw[iq * 640 + (quad * 4 + r) * 40 + jj * 16 + lo] = u.us[0];
                }

        bfx8 pf0 = *(const bfx8*)&Pw[lo * 40 + hi8];
        bfx8 pf1 = *(const bfx8*)&Pw[640 + lo * 40 + hi8];
        #pragma unroll
        for (int j = 0; j < 8; ++j) {
            O[0][j] = __builtin_amdgcn_mfma_f32_16x16x32_bf16(pf0, vf[j], O[0][j], 0, 0, 0);
            O[1][j] = __builtin_amdgcn_mfma_f32_16x16x32_bf16(pf1, vf[j], O[1][j], 0, 0, 0);
        }

        #pragma unroll
        for (int jj = 0; jj < 2; ++jj)
            #pragma unroll
            for (int c4 = 0; c4 < 4; ++c4) kcur[jj][c4] = knxt[jj][c4];
    }

    #pragma unroll
    for (int off = 1; off < 16; off <<= 1)
        #pragma unroll
        for (int iq = 0; iq < 2; ++iq)
            #pragma unroll
            for (int r = 0; r < 4; ++r) lsum[iq][r] += __shfl_xor(lsum[iq][r], off, 64);

    // fp32 atomic accumulate into Oacc[b][row][col] (<=8 contenders per element)
    float* Ob = Oacc + (size_t)b * T_SEQ * DH;
    #pragma unroll
    for (int iq = 0; iq < 2; ++iq)
        #pragma unroll
        for (int j = 0; j < 8; ++j) {
            const int col = j * 16 + lo;
            #pragma unroll
            for (int r = 0; r < 4; ++r) {
                const int row = qbase + iq * 16 + quad * 4 + r;
                unsafeAtomicAdd(&Ob[(size_t)row * DH + col], O[iq][j][r]);
            }
        }
    if (lo == 0) {
        #pragma unroll
        for (int iq = 0; iq < 2; ++iq)
            #pragma unroll
            for (int r = 0; r < 4; ++r)
                unsafeAtomicAdd(&Lacc[(size_t)b * T_SEQ + qbase + iq * 16 + quad * 4 + r],
                                lsum[iq][r]);
    }
}

// ---------------- Kernel N: normalize out = Oacc / Lacc ----------------
// grid 512 x 256: thread = (row = gid>>4, 8 cols at (gid&15)*8)
__global__ __launch_bounds__(256) void normalize_kernel(
    const float* __restrict__ Oacc, const float* __restrict__ Lacc,
    float* __restrict__ out)
{
    const int gid = blockIdx.x * 256 + threadIdx.x;
    const int row = gid >> 4;
    const int d0  = (gid & 15) * 8;
    const float inv = 1.f / Lacc[row];
    float4 a = *(const float4*)(Oacc + (size_t)row * DH + d0);
    float4 b = *(const float4*)(Oacc + (size_t)row * DH + d0 + 4);
    *(float4*)(out + (size_t)row * DH + d0)     = make_float4(a.x*inv, a.y*inv, a.z*inv, a.w*inv);
    *(float4*)(out + (size_t)row * DH + d0 + 4) = make_float4(b.x*inv, b.y*inv, b.z*inv, b.w*inv);
}

extern "C" void kernel_launch(void* const* d_in, const int* in_sizes, int n_in,
                              void* d_out, int out_size, void* d_ws, size_t ws_size,
                              hipStream_t stream) {
    const float* x     = (const float*)d_in[0];
    const float* Wq    = (const float*)d_in[1];
    const float* Wk    = (const float*)d_in[2];
    const float* Wv    = (const float*)d_in[3];
    const float* theta = (const float*)d_in[4];
    float* out = (float*)d_out;

    const int M = in_sizes[0] / D_MODEL;   // B*T = 8192
    const int B = M / T_SEQ;               // 4

    // ws: QF | KF | VF (2 MB each) | Oacc fp32 16.8 MB.. no: B*T*DH*4 = 4 MB | Lacc 32 KB.
    // Wb (768 KB) aliases Oacc head: wcvt -> qkv(reads Wb) -> zero(wipes) -> attn -> norm.
    __bf16* QF   = (__bf16*)d_ws;
    __bf16* KF   = QF + (size_t)B * FRAG_B;
    __bf16* VF   = KF + (size_t)B * FRAG_B;
    float*  Oacc = (float*)(VF + (size_t)B * FRAG_B);
    float*  Lacc = Oacc + (size_t)B * T_SEQ * DH;
    __bf16* Wb   = (__bf16*)Oacc;

    wcvt_kernel<<<dim3(192), 256, 0, stream>>>(Wq, Wk, Wv, Wb);
    qkv_kernel<<<dim3(3 * (M / 64)), 256, 0, stream>>>(x, Wb, theta, QF, KF, VF, M);
    zero_kernel<<<dim3((B * T_SEQ * DH + B * T_SEQ) / 1024), 256, 0, stream>>>(Oacc);
    attn_partial_kernel<<<dim3(T_SEQ / 32, 8, B), 64, 0, stream>>>(QF, KF, VF, Oacc, Lacc);
    normalize_kernel<<<dim3(B * T_SEQ * DH / 2048), 256, 0, stream>>>(Oacc, Lacc, out);
}

// Round 11
// 124.561 us; speedup vs baseline: 1.0713x; 1.0713x over previous
//
#include <hip/hip_runtime.h>
#include <math.h>

#define T_SEQ 2048
#define D_MODEL 1024
#define DH 128
#define SLOTS 288          // per batch: sum_{qt=0..63} ((qt>>3)+1)
#define FRAG_B 262144      // frag-plane elems per batch: 128*4*512 (= 64*8*512)

typedef __bf16 bfx8 __attribute__((ext_vector_type(8)));
typedef float f32x4 __attribute__((ext_vector_type(4)));

union U16x8 { uint4 u4; unsigned int ui[4]; unsigned short us[8]; __bf16 bf[8]; bfx8 v; };

__device__ inline uint4 cvt8u(float4 a, float4 b) {
    U16x8 u;
    u.bf[0] = (__bf16)a.x; u.bf[1] = (__bf16)a.y; u.bf[2] = (__bf16)a.z; u.bf[3] = (__bf16)a.w;
    u.bf[4] = (__bf16)b.x; u.bf[5] = (__bf16)b.y; u.bf[6] = (__bf16)b.z; u.bf[7] = (__bf16)b.w;
    return u.u4;
}

__device__ inline int slot_base32(int qt) {   // sum_{i<qt} ((i>>3)+1)
    int g = qt >> 3, j = qt & 7;
    return 4 * g * (g + 1) + j * (g + 1);
}

// ---------------- Kernel P: prep — x -> xF (A-frag order), W -> WF (B-frag order) ----
// blocks [0, nxb): xcvt. 64m x 64k tile via LDS transpose-to-frag; coalesced in/out.
// blocks [nxb, nxb+192): wcvt. One-pass gather of 1.5 MB W into B-frag order.
// xF frag id = mt16*32 + kc : lane ln -> x[mt16*16 + (ln&15)][kc*32 + (ln>>4)*8 + e]
// WF frag id = (wsel*32 + kc)*8 + j : lane ln -> W[j*16+(ln&15)][kc*32+(ln>>4)*8+e]
__global__ __launch_bounds__(256) void prep_kernel(
    const float* __restrict__ x,
    const float* __restrict__ Wq, const float* __restrict__ Wk,
    const float* __restrict__ Wv,
    __bf16* __restrict__ xF, __bf16* __restrict__ WF, int nxb)
{
    const int bi = blockIdx.x;
    const int tid = threadIdx.x;

    if (bi < nxb) {
        __shared__ __align__(16) unsigned short Xs[64 * 72];   // 9 KB
        const int m0 = (bi >> 4) * 64;
        const int k0 = (bi & 15) * 64;
        const int row = tid >> 2, cs = (tid & 3) * 16;
        const float* xp = x + (size_t)(m0 + row) * D_MODEL + k0 + cs;
        float4 a0 = *(const float4*)xp;
        float4 a1 = *(const float4*)(xp + 4);
        float4 a2 = *(const float4*)(xp + 8);
        float4 a3 = *(const float4*)(xp + 12);
        *(uint4*)&Xs[row * 72 + cs]     = cvt8u(a0, a1);
        *(uint4*)&Xs[row * 72 + cs + 8] = cvt8u(a2, a3);
        __syncthreads();
        const int L = tid & 63;
        #pragma unroll
        for (int rr = 0; rr < 2; ++rr) {
            const int fid = rr * 4 + (tid >> 6);   // 8 local frags: mtl(4) x kcl(2)
            const int mtl = fid >> 1, kcl = fid & 1;
            uint4 d = *(const uint4*)&Xs[(mtl * 16 + (L & 15)) * 72 + kcl * 32 + (L >> 4) * 8];
            const size_t frag = (size_t)((m0 >> 4) + mtl) * 32 + (k0 >> 5) + kcl;
            *(uint4*)&xF[frag * 512 + L * 8] = d;
        }
    } else {
        const int i = (bi - nxb) * 256 + tid;      // 49152 threads
        const int wsel = i >> 14;
        const int i2 = i & 16383;
        const int kc = i2 >> 9, j = (i2 >> 6) & 7, ln = i2 & 63;
        const int lo = ln & 15, quad = ln >> 4;
        const float* src = (wsel == 0) ? Wq : (wsel == 1) ? Wk : Wv;
        const float* p = src + (size_t)(j * 16 + lo) * D_MODEL + kc * 32 + quad * 8;
        float4 a = *(const float4*)p;
        float4 b = *(const float4*)(p + 4);
        *(uint4*)&WF[(size_t)((wsel * 32 + kc) * 8 + j) * 512 + ln * 8] = cvt8u(a, b);
    }
}

// ---------------- Kernel A: QKV — wave-autonomous frag GEMM + RoPE ----------------
// grid 3*256 single-wave blocks. Wave = (wsel, 32 m-rows), K-loop 32 steps:
// 2 xF frags + 8 WF frags (contiguous 1 KB L2-hot loads, depth-1 prefetch) + 16 MFMA.
// No barriers. Epilogue: RoPE (Q,K), C->frag permute via wave-private LDS, store
// QF/KF (A-frag) or VF (B-frag) in the exact attn input formats.
__global__ __launch_bounds__(64) void qkv_kernel(
    const __bf16* __restrict__ xF, const __bf16* __restrict__ WF,
    const float* __restrict__ theta,
    __bf16* __restrict__ QF, __bf16* __restrict__ KF, __bf16* __restrict__ VF)
{
    __shared__ __align__(16) unsigned short T[32 * 136];   // 8.7 KB wave-private

    const int bx = blockIdx.x;
    const int wsel = bx >> 8;
    const int m0 = (bx & 255) * 32;

    const int ln = threadIdx.x;
    const int lo = ln & 15, quad = ln >> 4;

    const __bf16* WFp = WF + (size_t)wsel * (32 * 8 * 512);
    const size_t xf0 = ((size_t)(m0 >> 4)) * 32;   // frag base for iq=0

    bfx8 xc[2], xn[2], wc[8], wn[8];
    #pragma unroll
    for (int iq = 0; iq < 2; ++iq)
        xc[iq] = *(const bfx8*)&xF[(xf0 + iq * 32) * 512 + ln * 8];
    #pragma unroll
    for (int j = 0; j < 8; ++j)
        wc[j] = *(const bfx8*)&WFp[(size_t)j * 512 + ln * 8];

    f32x4 acc[2][8];
    #pragma unroll
    for (int iq = 0; iq < 2; ++iq)
        #pragma unroll
        for (int j = 0; j < 8; ++j) acc[iq][j] = (f32x4)(0.f);

    for (int kc = 0; kc < 32; ++kc) {
        if (kc < 31) {
            #pragma unroll
            for (int iq = 0; iq < 2; ++iq)
                xn[iq] = *(const bfx8*)&xF[(xf0 + iq * 32 + kc + 1) * 512 + ln * 8];
            #pragma unroll
            for (int j = 0; j < 8; ++j)
                wn[j] = *(const bfx8*)&WFp[(size_t)((kc + 1) * 8 + j) * 512 + ln * 8];
        }
        #pragma unroll
        for (int j = 0; j < 8; ++j) {
            acc[0][j] = __builtin_amdgcn_mfma_f32_16x16x32_bf16(xc[0], wc[j], acc[0][j], 0, 0, 0);
            acc[1][j] = __builtin_amdgcn_mfma_f32_16x16x32_bf16(xc[1], wc[j], acc[1][j], 0, 0, 0);
        }
        if (kc < 31) {
            xc[0] = xn[0]; xc[1] = xn[1];
            #pragma unroll
            for (int j = 0; j < 8; ++j) wc[j] = wn[j];
        }
    }

    const int b = m0 >> 11;
    const int mloc0 = m0 & (T_SEQ - 1);

    if (wsel < 2) {
        // C-layout: col h = j*16+lo, row m = iq*16 + quad*4 + r. RoPE, then per-iq
        // LDS bounce [m16][h128] (stride 136) -> A-frag reads (contiguous h).
        __bf16* dstP = (wsel == 0 ? QF : KF) + (size_t)b * FRAG_B;
        const int t16l = mloc0 >> 4;
        #pragma unroll
        for (int iq = 0; iq < 2; ++iq) {
            #pragma unroll
            for (int j = 0; j < 8; ++j) {
                const int h = j * 16 + lo;
                const float th = theta[h];
                #pragma unroll
                for (int r = 0; r < 4; ++r) {
                    const int pos = mloc0 + iq * 16 + quad * 4 + r + 1;
                    float v = acc[iq][j][r];
                    float partner = __shfl_xor(v, 1, 64);
                    float ang = (float)pos * th;
                    float rev = ang * 0.15915494309189535f;   // 1/(2*pi)
                    rev -= floorf(rev);
                    float sn = __builtin_amdgcn_sinf(rev);
                    float cs = __builtin_amdgcn_cosf(rev);
                    float res = (h & 1) ? (v * cs - partner * sn)
                                        : (v * cs + partner * sn);
                    U16x8 u; u.bf[0] = (__bf16)res;
                    T[(quad * 4 + r) * 136 + h] = u.us[0];
                }
            }
            // wave-private LDS: in-order DS ops, no barrier needed
            #pragma unroll
            for (int c4 = 0; c4 < 4; ++c4) {
                uint4 d = *(const uint4*)&T[(ln & 15) * 136 + c4 * 32 + (ln >> 4) * 8];
                *(uint4*)&dstP[(size_t)((t16l + iq) * 4 + c4) * 512 + ln * 8] = d;
            }
        }
    } else {
        // V: C (col lo = d, row quad*4+r = t) -> B-frag [t = quad*8+e][d = lo]
        const int kt32 = mloc0 >> 5;
        #pragma unroll
        for (int iq = 0; iq < 2; ++iq)
            #pragma unroll
            for (int j = 0; j < 8; ++j)
                #pragma unroll
                for (int r = 0; r < 4; ++r) {
                    U16x8 u; u.bf[0] = (__bf16)acc[iq][j][r];
                    T[(iq * 16 + quad * 4 + r) * 136 + j * 16 + lo] = u.us[0];
                }
        __bf16* dstP = VF + (size_t)b * FRAG_B;
        #pragma unroll
        for (int j = 0; j < 8; ++j) {
            U16x8 u;
            #pragma unroll
            for (int e = 0; e < 8; ++e)
                u.us[e] = T[((ln >> 4) * 8 + e) * 136 + j * 16 + (ln & 15)];
            *(uint4*)&dstP[(size_t)(kt32 * 8 + j) * 512 + ln * 8] = u.u4;
        }
    }
}

// ---------------- Kernel B: wave-autonomous attention, all-coalesced ----------------
// grid (64 qt, 8 c, B), block 64 = ONE wave: 32 q-rows x 256-k chunk, <=8 tiles of 32.
// Every operand load = contiguous 1 KB wave read; K frags prefetched depth-1.
__global__ __launch_bounds__(64) void attn_partial_kernel(
    const __bf16* __restrict__ QF, const __bf16* __restrict__ KF,
    const __bf16* __restrict__ VF,
    __bf16* __restrict__ Opb, float* __restrict__ Ll)
{
    const int qt = blockIdx.x, c = blockIdx.y, b = blockIdx.z;
    const int qbase = qt * 32;
    const int kstart = c << 8;
    if (kstart > qbase) return;
    const int nt = min(8, (qbase + 32 - kstart) >> 5);

    __shared__ __align__(16) unsigned short Pw[2 * 640];

    const int ln = threadIdx.x;
    const int lo = ln & 15, quad = ln >> 4;
    const int hi8 = quad * 8;

    const __bf16* QFb = QF + (size_t)b * FRAG_B;
    const __bf16* KFb = KF + (size_t)b * FRAG_B;
    const __bf16* VFb = VF + (size_t)b * FRAG_B;

    bfx8 qf[2][4];
    #pragma unroll
    for (int iq = 0; iq < 2; ++iq)
        #pragma unroll
        for (int c4 = 0; c4 < 4; ++c4)
            qf[iq][c4] = *(const bfx8*)&QFb[(size_t)((qt * 2 + iq) * 4 + c4) * 512 + ln * 8];

    f32x4 O[2][8];
    #pragma unroll
    for (int iq = 0; iq < 2; ++iq)
        #pragma unroll
        for (int j = 0; j < 8; ++j) O[iq][j] = (f32x4)(0.f);
    float lsum[2][4];
    #pragma unroll
    for (int iq = 0; iq < 2; ++iq)
        #pragma unroll
        for (int r = 0; r < 4; ++r) lsum[iq][r] = 0.f;

    bfx8 kcur[2][4], knxt[2][4];
    #pragma unroll
    for (int jj = 0; jj < 2; ++jj)
        #pragma unroll
        for (int c4 = 0; c4 < 4; ++c4)
            kcur[jj][c4] = *(const bfx8*)&KFb[(size_t)(((kstart >> 4) + jj) * 4 + c4) * 512 + ln * 8];

    for (int kt = 0; kt < nt; ++kt) {
        const int k0 = kstart + kt * 32;
        bfx8 vf[8];
        #pragma unroll
        for (int j = 0; j < 8; ++j)
            vf[j] = *(const bfx8*)&VFb[(size_t)((k0 >> 5) * 8 + j) * 512 + ln * 8];
        if (kt + 1 < nt) {
            const int kn16 = (k0 + 32) >> 4;
            #pragma unroll
            for (int jj = 0; jj < 2; ++jj)
                #pragma unroll
                for (int c4 = 0; c4 < 4; ++c4)
                    knxt[jj][c4] = *(const bfx8*)&KFb[(size_t)((kn16 + jj) * 4 + c4) * 512 + ln * 8];
        }

        f32x4 s4[2][2];
        #pragma unroll
        for (int iq = 0; iq < 2; ++iq)
            #pragma unroll
            for (int jj = 0; jj < 2; ++jj) s4[iq][jj] = (f32x4)(0.f);
        #pragma unroll
        for (int c4 = 0; c4 < 4; ++c4)
            #pragma unroll
            for (int iq = 0; iq < 2; ++iq)
                #pragma unroll
                for (int jj = 0; jj < 2; ++jj)
                    s4[iq][jj] = __builtin_amdgcn_mfma_f32_16x16x32_bf16(qf[iq][c4], kcur[jj][c4], s4[iq][jj], 0, 0, 0);

        const bool needMask = (k0 + 31 > qbase);
        #pragma unroll
        for (int iq = 0; iq < 2; ++iq)
            #pragma unroll
            for (int jj = 0; jj < 2; ++jj)
                #pragma unroll
                for (int r = 0; r < 4; ++r) {
                    const int col = k0 + jj * 16 + lo;
                    const int row = qbase + iq * 16 + quad * 4 + r;
                    float p = __expf(s4[iq][jj][r] * 0.03125f);   // scale 1024^-0.5
                    if (needMask && col > row) p = 0.f;
                    lsum[iq][r] += p;
                    U16x8 u; u.bf[0] = (__bf16)p;
                    Pw[iq * 640 + (quad * 4 + r) * 40 + jj * 16 + lo] = u.us[0];
                }

        bfx8 pf0 = *(const bfx8*)&Pw[lo * 40 + hi8];
        bfx8 pf1 = *(const bfx8*)&Pw[640 + lo * 40 + hi8];
        #pragma unroll
        for (int j = 0; j < 8; ++j) {
            O[0][j] = __builtin_amdgcn_mfma_f32_16x16x32_bf16(pf0, vf[j], O[0][j], 0, 0, 0);
            O[1][j] = __builtin_amdgcn_mfma_f32_16x16x32_bf16(pf1, vf[j], O[1][j], 0, 0, 0);
        }

        #pragma unroll
        for (int jj = 0; jj < 2; ++jj)
            #pragma unroll
            for (int c4 = 0; c4 < 4; ++c4) kcur[jj][c4] = knxt[jj][c4];
    }

    #pragma unroll
    for (int off = 1; off < 16; off <<= 1)
        #pragma unroll
        for (int iq = 0; iq < 2; ++iq)
            #pragma unroll
            for (int r = 0; r < 4; ++r) lsum[iq][r] += __shfl_xor(lsum[iq][r], off, 64);

    const size_t sb = (size_t)b * SLOTS + slot_base32(qt) + c;
    #pragma unroll
    for (int iq = 0; iq < 2; ++iq)
        #pragma unroll
        for (int j = 0; j < 8; ++j) {
            U16x8 u;
            u.bf[0] = (__bf16)O[iq][j][0]; u.bf[1] = (__bf16)O[iq][j][1];
            u.bf[2] = (__bf16)O[iq][j][2]; u.bf[3] = (__bf16)O[iq][j][3];
            *(uint2*)&Opb[((sb * 2 + iq) * 8 + j) * 256 + ln * 4] = make_uint2(u.ui[0], u.ui[1]);
        }
    if (lo == 0) {
        #pragma unroll
        for (int iq = 0; iq < 2; ++iq)
            #pragma unroll
            for (int r = 0; r < 4; ++r)
                Ll[sb * 32 + iq * 16 + quad * 4 + r] = lsum[iq][r];
    }
}

// ---------------- Kernel C: merge partials (coalesced frag-flat reads) ----------------
__global__ __launch_bounds__(128) void attn_merge_kernel(
    const __bf16* __restrict__ Opb, const float* __restrict__ Ll,
    float* __restrict__ out)
{
    const int qt = blockIdx.x, b = blockIdx.y, j = blockIdx.z;
    const int g = qt >> 3, nc = g + 1;
    const size_t base = (size_t)b * SLOTS + slot_base32(qt);

    __shared__ float Lsh[8][32];
    const int tid = threadIdx.x;
    const int iq = tid >> 6, ln = tid & 63;
    const int lo = ln & 15, quad = ln >> 4;

    for (int idx = tid; idx < nc * 32; idx += 128)
        Lsh[idx >> 5][idx & 31] = Ll[(base + (idx >> 5)) * 32 + (idx & 31)];
    __syncthreads();

    float acc[4] = {0.f, 0.f, 0.f, 0.f};
    for (int cc = 0; cc < nc; ++cc) {
        uint2 d = *(const uint2*)&Opb[(((base + cc) * 2 + iq) * 8 + j) * 256 + ln * 4];
        U16x8 u; u.ui[0] = d.x; u.ui[1] = d.y;
        #pragma unroll
        for (int r = 0; r < 4; ++r) acc[r] += (float)u.bf[r];
    }

    #pragma unroll
    for (int r = 0; r < 4; ++r) {
        const int row = iq * 16 + quad * 4 + r;
        float l = 0.f;
        for (int cc = 0; cc < nc; ++cc) l += Lsh[cc][row];
        out[((size_t)b * T_SEQ + qt * 32 + row) * DH + j * 16 + lo] = acc[r] / l;
    }
}

extern "C" void kernel_launch(void* const* d_in, const int* in_sizes, int n_in,
                              void* d_out, int out_size, void* d_ws, size_t ws_size,
                              hipStream_t stream) {
    const float* x     = (const float*)d_in[0];
    const float* Wq    = (const float*)d_in[1];
    const float* Wk    = (const float*)d_in[2];
    const float* Wv    = (const float*)d_in[3];
    const float* theta = (const float*)d_in[4];
    float* out = (float*)d_out;

    const int M = in_sizes[0] / D_MODEL;   // B*T = 8192
    const int B = M / T_SEQ;               // 4

    // ws (~268 MB available): xF 16.8 MB | WF 0.75 | QF/KF/VF 2.1 each | Opb 9.4 | Ll
    __bf16* xF  = (__bf16*)d_ws;                     // M*1024 bf16
    __bf16* WF  = xF + (size_t)M * D_MODEL;          // 3*32*8*512
    __bf16* QF  = WF + (size_t)3 * 32 * 8 * 512;
    __bf16* KF  = QF + (size_t)B * FRAG_B;
    __bf16* VF  = KF + (size_t)B * FRAG_B;
    __bf16* Opb = VF + (size_t)B * FRAG_B;
    float*  Ll  = (float*)(Opb + (size_t)B * SLOTS * 2 * 8 * 256);

    const int nxb = (M / 64) * 16;                   // 2048 xcvt blocks
    prep_kernel<<<dim3(nxb + 192), 256, 0, stream>>>(x, Wq, Wk, Wv, xF, WF, nxb);
    qkv_kernel<<<dim3(3 * (M / 32)), 64, 0, stream>>>(xF, WF, theta, QF, KF, VF);
    attn_partial_kernel<<<dim3(T_SEQ / 32, 8, B), 64, 0, stream>>>(QF, KF, VF, Opb, Ll);
    attn_merge_kernel<<<dim3(T_SEQ / 32, B, 8), 128, 0, stream>>>(Opb, Ll, out);
}